// Round 9
// baseline (88.350 us; speedup 1.0000x reference)
//
#include <hip/hip_runtime.h>

// LSH attention (Reformer-style) on MI355X.
// out0 == v exactly -> fused float4 copy (issued last, off all barriers).
// out1 = buckets via MFMA bf16 hi/lo split (3 products, err <= ~1e-3),
// certified packed-key argmax (MARGIN=8e-3 >= 3x total error bound);
// ambiguous rows repaired in fp64 (bit-exact path, proven R1-R8).
// R9: occupancy attack. 512-thread blocks (8 waves), grid 1024 -> 4
// blocks/CU (LDS 4x36.9=147.5 KB <= 160), __launch_bounds__(512,8) ->
// 64-VGPR budget -> 32 waves/CU (2x R7/R8). Wave = 16 rows x 2 h; A
// split once reused across h; B streamed from LDS (no hoist) to keep
// peak live ~55 VGPR. Math identical to passing R7/R8.

namespace {
constexpr int S_LEN   = 8192;
constexpr int D_DIM   = 64;
constexpr int N_HASH  = 8;
constexpr int N_BUCK  = 128;
constexpr int T_TILE  = 128;   // rows per block: 8 waves x 16 rows
constexpr int THREADS = 512;
constexpr int BATCH   = 4;
constexpr int H_PER   = 2;     // h values per block
constexpr int BSTRIDE = 72;    // LDS shorts per n-row (64 + 8 pad)
constexpr float MARGIN = 8e-3f;
constexpr long long OUT0_ELEMS = (long long)BATCH * S_LEN * D_DIM;
}

typedef __attribute__((ext_vector_type(8))) short bf16x8;
typedef __attribute__((ext_vector_type(4))) float f32x4;
typedef __attribute__((ext_vector_type(4))) unsigned uint4v;

// dword = [lo16 = hi16(x0) | hi16 = hi16(x1)]  (bf16 truncation pack)
__device__ __forceinline__ unsigned pack_hi16(unsigned u0, unsigned u1) {
  return __builtin_amdgcn_perm(u1, u0, 0x07060302u);
}

__global__ __launch_bounds__(THREADS, 8) void lsh_mfma_kernel(
    const float* __restrict__ qk, const float* __restrict__ v,
    const float* __restrict__ rot, float* __restrict__ out) {
  const int b    = blockIdx.z;
  const int hb   = blockIdx.y;   // h-pair index (h = hb*2 + hh)
  const int tile = blockIdx.x;
  const int tid  = threadIdx.x;
  const int wave = tid >> 6;
  const int lane = tid & 63;
  const int col  = lane & 15;    // MFMA m / n index
  const int quad = lane >> 4;    // MFMA k-group / C-row group

  __shared__ __align__(16) unsigned short lbh[H_PER][64 * BSTRIDE];
  __shared__ __align__(16) unsigned short lbl[H_PER][64 * BSTRIDE];

  // ---- stage rot[.,h,.] -> LDS bf16 hi/lo, k-contiguous per n ----
  // 512 threads: n = tid>>3 (0..63), k0 = (tid&7)*8; 8 floats/thread/hh.
  {
    const int n  = tid >> 3;
    const int k0 = (tid & 7) * 8;
#pragma unroll
    for (int hh = 0; hh < H_PER; ++hh) {
      const float* rp = rot + (hb * H_PER + hh) * 64 + n;
      unsigned hu[4], lu[4];
#pragma unroll
      for (int p = 0; p < 4; ++p) {
        const float x0 = rp[(size_t)(k0 + 2 * p) * 512];
        const float x1 = rp[(size_t)(k0 + 2 * p + 1) * 512];
        const unsigned u0 = __float_as_uint(x0);
        const unsigned u1 = __float_as_uint(x1);
        const float l0 = x0 - __uint_as_float(u0 & 0xffff0000u);
        const float l1 = x1 - __uint_as_float(u1 & 0xffff0000u);
        hu[p] = pack_hi16(u0, u1);
        lu[p] = pack_hi16(__float_as_uint(l0), __float_as_uint(l1));
      }
      const int off = n * BSTRIDE + k0;
      *(uint4v*)&lbh[hh][off] = uint4v{hu[0], hu[1], hu[2], hu[3]};
      *(uint4v*)&lbl[hh][off] = uint4v{lu[0], lu[1], lu[2], lu[3]};
    }
  }

  // ---- A fragment: 16 rows per wave, split once, reused for both h ----
  const int trow0 = tile * T_TILE + wave * 16;
  bf16x8 Ah[2], Al[2];   // [kk]
  {
    const float* qrow = qk + ((size_t)b * S_LEN + trow0 + col) * D_DIM;
#pragma unroll
    for (int kk = 0; kk < 2; ++kk) {
      float qb[8];
      *(float4*)&qb[0] = *(const float4*)(qrow + kk * 32 + quad * 8);
      *(float4*)&qb[4] = *(const float4*)(qrow + kk * 32 + quad * 8 + 4);
      unsigned hu[4], lu[4];
#pragma unroll
      for (int p = 0; p < 4; ++p) {
        const unsigned u0 = __float_as_uint(qb[2 * p]);
        const unsigned u1 = __float_as_uint(qb[2 * p + 1]);
        const float l0 = qb[2 * p]     - __uint_as_float(u0 & 0xffff0000u);
        const float l1 = qb[2 * p + 1] - __uint_as_float(u1 & 0xffff0000u);
        hu[p] = pack_hi16(u0, u1);
        lu[p] = pack_hi16(__float_as_uint(l0), __float_as_uint(l1));
      }
      Ah[kk] = __builtin_bit_cast(bf16x8, uint4v{hu[0], hu[1], hu[2], hu[3]});
      Al[kk] = __builtin_bit_cast(bf16x8, uint4v{lu[0], lu[1], lu[2], lu[3]});
    }
  }
  __syncthreads();

  const int basec0 = 127 - col;  // key code base: 127 - (nt*16+col) - 64*sign
  unsigned rmask[H_PER] = {0u, 0u};  // ambiguous rows, bit = row in [0,16)

#pragma unroll
  for (int hh = 0; hh < H_PER; ++hh) {
    const int h = hb * H_PER + hh;
    float* outb = out + OUT0_ELEMS + ((size_t)(b * N_HASH + h)) * S_LEN + tile * T_TILE;

    // ---- split GEMM: C = Ah*Bh + Ah*Bl + Al*Bh, B streamed from LDS ----
    f32x4 acc[4];
#pragma unroll
    for (int nt = 0; nt < 4; ++nt) {
      f32x4 c = {0.f, 0.f, 0.f, 0.f};
#pragma unroll
      for (int kk = 0; kk < 2; ++kk) {
        const int boff = (nt * 16 + col) * BSTRIDE + kk * 32 + quad * 8;
        const bf16x8 bh = *(const bf16x8*)&lbh[hh][boff];
        const bf16x8 bl = *(const bf16x8*)&lbl[hh][boff];
        c = __builtin_amdgcn_mfma_f32_16x16x32_bf16(Ah[kk], bh, c, 0, 0, 0);
        c = __builtin_amdgcn_mfma_f32_16x16x32_bf16(Ah[kk], bl, c, 0, 0, 0);
        c = __builtin_amdgcn_mfma_f32_16x16x32_bf16(Al[kk], bh, c, 0, 0, 0);
      }
      acc[nt] = c;
    }

    // ---- packed-key certified top-2 argmax (see R7 comment) ----
#pragma unroll
    for (int reg = 0; reg < 4; ++reg) {
      unsigned m1 = 0u, m2 = 0u;
#pragma unroll
      for (int nt = 0; nt < 4; ++nt) {
        const unsigned u = __float_as_uint(acc[nt][reg]);
        const unsigned a = u & 0x7fffffffu;
        const unsigned code = (unsigned)(basec0 - nt * 16) - ((u >> 25) & 0x40u);
        const unsigned key = (a & 0xffffff80u) | code;
        const unsigned t = min(m1, key);
        m2 = max(m2, t);
        m1 = max(m1, key);
      }
#pragma unroll
      for (int m = 1; m < 16; m <<= 1) {
        const unsigned o1 = (unsigned)__shfl_xor((int)m1, m);
        const unsigned o2 = (unsigned)__shfl_xor((int)m2, m);
        const unsigned t = min(m1, o1);
        m2 = max(max(m2, o2), t);
        m1 = max(m1, o1);
      }
      bool amb = false;
      if (col == 0) {
        const float v1 = __uint_as_float(m1 & 0xffffff80u);
        const float v2 = __uint_as_float(m2 & 0xffffff80u);
        amb = (v1 - v2 < MARGIN);
        if (!amb) {
          const int t_local = wave * 16 + quad * 4 + reg;
          const int idx = 127 - (int)(m1 & 0x7fu);
          outb[t_local] = (float)(idx + h * N_BUCK);
        }
      }
      // collect ambiguous rows into a wave-uniform mask (no LDS/atomics)
      const unsigned long long bal = __ballot(amb);  // bits at lanes 0/16/32/48
      if (bal) {
        const unsigned q0 = (unsigned)(bal & 1ull);
        const unsigned q1 = (unsigned)((bal >> 16) & 1ull);
        const unsigned q2 = (unsigned)((bal >> 32) & 1ull);
        const unsigned q3 = (unsigned)((bal >> 48) & 1ull);
        const unsigned spread = q0 | (q1 << 4) | (q2 << 8) | (q3 << 12);
        rmask[hh] |= spread << reg;   // bit = quad*4 + reg
      }
    }
  }

  // ---- rare fp64 repair: wave-private, no barrier (mask is wave-uniform) ----
#pragma unroll
  for (int hh = 0; hh < H_PER; ++hh) {
    unsigned m = rmask[hh];
    const int h = hb * H_PER + hh;
    while (m) {
      const int row = __builtin_ctz(m);
      m &= m - 1;
      const int tl = wave * 16 + row;
      const float* qrow = qk + ((size_t)b * S_LEN + tile * T_TILE + tl) * D_DIM;
      double dot = 0.0;
#pragma unroll 8
      for (int f = 0; f < D_DIM; ++f)
        dot = fma((double)qrow[f], (double)rot[(size_t)f * 512 + h * 64 + lane], dot);
      double vp = dot, vn = -dot;
      int ip = lane, in_ = 64 + lane;
#pragma unroll
      for (int s = 1; s < 64; s <<= 1) {
        const double ovp = __shfl_xor(vp, s);
        const int   oip = __shfl_xor(ip, s);
        if (ovp > vp || (ovp == vp && oip < ip)) { vp = ovp; ip = oip; }
        const double ovn = __shfl_xor(vn, s);
        const int   oin = __shfl_xor(in_, s);
        if (ovn > vn || (ovn == vn && oin < in_)) { vn = ovn; in_ = oin; }
      }
      if (lane == 0) {
        const int bucket = (vp >= vn) ? ip : in_;
        out[OUT0_ELEMS + ((size_t)(b * N_HASH + h)) * S_LEN + tile * T_TILE + tl] =
            (float)(bucket + h * N_BUCK);
      }
    }
  }

  // ---- fused out0 = v copy, issued LAST: 1024 blocks x 512 x 1 float4 ----
  {
    const int bid = blockIdx.x + gridDim.x * (blockIdx.y + gridDim.y * blockIdx.z);
    const int base = bid * THREADS + tid;
    ((float4*)out)[base] = ((const float4*)v)[base];
  }
}

extern "C" void kernel_launch(void* const* d_in, const int* in_sizes, int n_in,
                              void* d_out, int out_size, void* d_ws, size_t ws_size,
                              hipStream_t stream) {
  const float* qk  = (const float*)d_in[0];
  const float* v   = (const float*)d_in[1];
  const float* rot = (const float*)d_in[2];
  float* out = (float*)d_out;

  dim3 grid(S_LEN / T_TILE, N_HASH / H_PER, BATCH);
  lsh_mfma_kernel<<<grid, THREADS, 0, stream>>>(qk, v, rot, out);
}

// Round 10
// 84.749 us; speedup vs baseline: 1.0425x; 1.0425x over previous
//
#include <hip/hip_runtime.h>

// LSH attention (Reformer-style) on MI355X.  [R10 = exact revert to R7 best]
// out0 == v exactly -> fused float4 copy.
// out1 = buckets via MFMA bf16 hi/lo split (3 products, err <= ~1e-3),
// certified packed-key argmax (MARGIN=8e-3 >= 3x total error bound);
// ambiguous rows repaired in fp64 (proven bit-exact path, R1-R6).
// R7: 2 h per block -> grid 1024 = 4 blocks/CU fully resident (no
// residency tail), A-frags split once for both h; epilogue rebuilt on
// u32 packed keys (|v| high-bits | 127-concat_idx): +/- pair collapse,
// max/min/max3 merges, ties/zeros -> repair. v_perm packs hi/lo pairs.
// R8 (schedule restructure) and R9 (2x occupancy) both regressed ~3 us:
// kernel is at its structural floor; totals dominated by harness resets.

namespace {
constexpr int S_LEN   = 8192;
constexpr int D_DIM   = 64;
constexpr int N_HASH  = 8;
constexpr int N_BUCK  = 128;
constexpr int T_TILE  = 128;   // rows per block: 4 waves x 2 mt x 16
constexpr int THREADS = 256;
constexpr int BATCH   = 4;
constexpr int H_PER   = 2;     // h values per block
constexpr int BSTRIDE = 72;    // LDS shorts per n-row (64 + 8 pad)
constexpr float MARGIN = 8e-3f;
constexpr long long OUT0_ELEMS = (long long)BATCH * S_LEN * D_DIM;
}

typedef __attribute__((ext_vector_type(8))) short bf16x8;
typedef __attribute__((ext_vector_type(4))) float f32x4;
typedef __attribute__((ext_vector_type(4))) unsigned uint4v;

// dword = [lo16 = hi16(x0) | hi16 = hi16(x1)]  (bf16 truncation pack)
__device__ __forceinline__ unsigned pack_hi16(unsigned u0, unsigned u1) {
  return __builtin_amdgcn_perm(u1, u0, 0x07060302u);
}

__global__ __launch_bounds__(THREADS, 4) void lsh_mfma_kernel(
    const float* __restrict__ qk, const float* __restrict__ v,
    const float* __restrict__ rot, float* __restrict__ out) {
  const int b    = blockIdx.z;
  const int hb   = blockIdx.y;   // h-pair index (h = hb*2 + hh)
  const int tile = blockIdx.x;
  const int tid  = threadIdx.x;
  const int wave = tid >> 6;
  const int lane = tid & 63;
  const int col  = lane & 15;    // MFMA m / n index
  const int quad = lane >> 4;    // MFMA k-group / C-row group

  __shared__ __align__(16) unsigned short lbh[H_PER][64 * BSTRIDE];
  __shared__ __align__(16) unsigned short lbl[H_PER][64 * BSTRIDE];
  __shared__ int s_cnt;
  __shared__ int s_list[H_PER * T_TILE];
  if (tid == 0) s_cnt = 0;

  // ---- fused out0 = v copy: 1024 blocks x 256 threads x 2 float4 ----
  {
    const int bid = blockIdx.x + gridDim.x * (blockIdx.y + gridDim.y * blockIdx.z);
    const int base = bid * 512 + tid;
    ((float4*)out)[base]       = ((const float4*)v)[base];
    ((float4*)out)[base + 256] = ((const float4*)v)[base + 256];
  }

  // ---- stage rot[.,h,.] -> LDS bf16 hi/lo, k-contiguous per n ----
  {
    const int n  = tid >> 2;
    const int k0 = (tid & 3) * 16;
#pragma unroll
    for (int hh = 0; hh < H_PER; ++hh) {
      const float* rp = rot + (hb * H_PER + hh) * 64 + n;
      unsigned hu[8], lu[8];
#pragma unroll
      for (int p = 0; p < 8; ++p) {
        const float x0 = rp[(size_t)(k0 + 2 * p) * 512];
        const float x1 = rp[(size_t)(k0 + 2 * p + 1) * 512];
        const unsigned u0 = __float_as_uint(x0);
        const unsigned u1 = __float_as_uint(x1);
        const float l0 = x0 - __uint_as_float(u0 & 0xffff0000u);
        const float l1 = x1 - __uint_as_float(u1 & 0xffff0000u);
        hu[p] = pack_hi16(u0, u1);
        lu[p] = pack_hi16(__float_as_uint(l0), __float_as_uint(l1));
      }
      const int off = n * BSTRIDE + k0;
      *(uint4v*)&lbh[hh][off]     = uint4v{hu[0], hu[1], hu[2], hu[3]};
      *(uint4v*)&lbh[hh][off + 8] = uint4v{hu[4], hu[5], hu[6], hu[7]};
      *(uint4v*)&lbl[hh][off]     = uint4v{lu[0], lu[1], lu[2], lu[3]};
      *(uint4v*)&lbl[hh][off + 8] = uint4v{lu[4], lu[5], lu[6], lu[7]};
    }
  }
  __syncthreads();

  // ---- A fragments for BOTH mt, split once, reused across both h ----
  const int trow0 = tile * T_TILE + wave * 32;
  bf16x8 Ah[2][2], Al[2][2];   // [mt][kk]
#pragma unroll
  for (int mt = 0; mt < 2; ++mt) {
    const float* qrow = qk + ((size_t)b * S_LEN + trow0 + mt * 16 + col) * D_DIM;
#pragma unroll
    for (int kk = 0; kk < 2; ++kk) {
      float qb[8];
      *(float4*)qb       = *(const float4*)(qrow + kk * 32 + quad * 8);
      *(float4*)(qb + 4) = *(const float4*)(qrow + kk * 32 + quad * 8 + 4);
      unsigned hu[4], lu[4];
#pragma unroll
      for (int p = 0; p < 4; ++p) {
        const unsigned u0 = __float_as_uint(qb[2 * p]);
        const unsigned u1 = __float_as_uint(qb[2 * p + 1]);
        const float l0 = qb[2 * p]     - __uint_as_float(u0 & 0xffff0000u);
        const float l1 = qb[2 * p + 1] - __uint_as_float(u1 & 0xffff0000u);
        hu[p] = pack_hi16(u0, u1);
        lu[p] = pack_hi16(__float_as_uint(l0), __float_as_uint(l1));
      }
      Ah[mt][kk] = __builtin_bit_cast(bf16x8, uint4v{hu[0], hu[1], hu[2], hu[3]});
      Al[mt][kk] = __builtin_bit_cast(bf16x8, uint4v{lu[0], lu[1], lu[2], lu[3]});
    }
  }

  const int basec0 = 127 - col;  // key code base: 127 - (nt*16+col) - 64*sign

#pragma unroll
  for (int hh = 0; hh < H_PER; ++hh) {
    const int h = hb * H_PER + hh;
    // hoist Bh fragments (32 VGPR); Bl streamed at use
    bf16x8 Bh[4][2];
#pragma unroll
    for (int nt = 0; nt < 4; ++nt)
#pragma unroll
      for (int kk = 0; kk < 2; ++kk)
        Bh[nt][kk] =
            *(const bf16x8*)&lbh[hh][(nt * 16 + col) * BSTRIDE + kk * 32 + quad * 8];

    float* outb = out + OUT0_ELEMS + ((size_t)(b * N_HASH + h)) * S_LEN + tile * T_TILE;

#pragma unroll
    for (int mt = 0; mt < 2; ++mt) {
      // ---- split GEMM: C = Ah*Bh + Ah*Bl + Al*Bh ----
      f32x4 acc[4];
#pragma unroll
      for (int nt = 0; nt < 4; ++nt) {
        f32x4 c = {0.f, 0.f, 0.f, 0.f};
#pragma unroll
        for (int kk = 0; kk < 2; ++kk) {
          const bf16x8 bl =
              *(const bf16x8*)&lbl[hh][(nt * 16 + col) * BSTRIDE + kk * 32 + quad * 8];
          c = __builtin_amdgcn_mfma_f32_16x16x32_bf16(Ah[mt][kk], Bh[nt][kk], c, 0, 0, 0);
          c = __builtin_amdgcn_mfma_f32_16x16x32_bf16(Ah[mt][kk], bl, c, 0, 0, 0);
          c = __builtin_amdgcn_mfma_f32_16x16x32_bf16(Al[mt][kk], Bh[nt][kk], c, 0, 0, 0);
        }
        acc[nt] = c;
      }

      // ---- packed-key certified top-2 argmax ----
      // key = (|v| & ~0x7F) | code, code = 127 - idx (idx = concat index,
      // +64 if the winning sign is negative). u32-monotone in value, ties
      // pick the smaller idx. -|v| candidates can't reach top-2 unless all
      // zero (-> gap 0 -> repair).
#pragma unroll
      for (int reg = 0; reg < 4; ++reg) {
        unsigned m1 = 0u, m2 = 0u;
#pragma unroll
        for (int nt = 0; nt < 4; ++nt) {
          const unsigned u = __float_as_uint(acc[nt][reg]);
          const unsigned a = u & 0x7fffffffu;
          const unsigned code = (unsigned)(basec0 - nt * 16) - ((u >> 25) & 0x40u);
          const unsigned key = (a & 0xffffff80u) | code;
          const unsigned t = min(m1, key);
          m2 = max(m2, t);
          m1 = max(m1, key);
        }
#pragma unroll
        for (int m = 1; m < 16; m <<= 1) {
          const unsigned o1 = (unsigned)__shfl_xor((int)m1, m);
          const unsigned o2 = (unsigned)__shfl_xor((int)m2, m);
          const unsigned t = min(m1, o1);
          m2 = max(max(m2, o2), t);
          m1 = max(m1, o1);
        }
        if (col == 0) {
          const float v1 = __uint_as_float(m1 & 0xffffff80u);
          const float v2 = __uint_as_float(m2 & 0xffffff80u);
          const int t_local = wave * 32 + mt * 16 + quad * 4 + reg;
          if (v1 - v2 < MARGIN) {
            s_list[atomicAdd(&s_cnt, 1)] = (hh << 8) | t_local;  // rare
          } else {
            const int idx = 127 - (int)(m1 & 0x7fu);
            outb[t_local] = (float)(idx + h * N_BUCK);
          }
        }
      }
    }
  }

  __syncthreads();

  // ---- rare fp64 repair: one wave per flagged row, lane = column i ----
  const int cnt = s_cnt;
  for (int it = wave; it < cnt; it += THREADS / 64) {
    const int e  = s_list[it];
    const int hh = e >> 8;
    const int tl = e & 255;
    const int h  = hb * H_PER + hh;
    const float* qrow = qk + ((size_t)b * S_LEN + tile * T_TILE + tl) * D_DIM;
    double dot = 0.0;
#pragma unroll 8
    for (int f = 0; f < D_DIM; ++f)
      dot = fma((double)qrow[f], (double)rot[(size_t)f * 512 + h * 64 + lane], dot);
    double vp = dot, vn = -dot;
    int ip = lane, in_ = 64 + lane;
#pragma unroll
    for (int m = 1; m < 64; m <<= 1) {
      const double ovp = __shfl_xor(vp, m);
      const int   oip = __shfl_xor(ip, m);
      if (ovp > vp || (ovp == vp && oip < ip)) { vp = ovp; ip = oip; }
      const double ovn = __shfl_xor(vn, m);
      const int   oin = __shfl_xor(in_, m);
      if (ovn > vn || (ovn == vn && oin < in_)) { vn = ovn; in_ = oin; }
    }
    if (lane == 0) {
      const int bucket = (vp >= vn) ? ip : in_;
      out[OUT0_ELEMS + ((size_t)(b * N_HASH + h)) * S_LEN + tile * T_TILE + tl] =
          (float)(bucket + h * N_BUCK);
    }
  }
}

extern "C" void kernel_launch(void* const* d_in, const int* in_sizes, int n_in,
                              void* d_out, int out_size, void* d_ws, size_t ws_size,
                              hipStream_t stream) {
  const float* qk  = (const float*)d_in[0];
  const float* v   = (const float*)d_in[1];
  const float* rot = (const float*)d_in[2];
  float* out = (float*)d_out;

  dim3 grid(S_LEN / T_TILE, N_HASH / H_PER, BATCH);
  lsh_mfma_kernel<<<grid, THREADS, 0, stream>>>(qk, v, rot, out);
}